// Round 15
// baseline (237.541 us; speedup 1.0000x reference)
//
#include <hip/hip_runtime.h>
#include <hip/hip_bf16.h>
#include <math.h>

#define D_MODEL 1024
#define BATCH   2
#define SEQ     2048
#define NHEAD   16
#define EHEAD   64
#define BS_ROWS (BATCH*SEQ)   // 4096
#define NSPLIT  4

typedef unsigned short ushort_t;
typedef unsigned long long u64;
typedef __attribute__((ext_vector_type(8))) short short8;   // 8 bf16 = 4 VGPRs
typedef __attribute__((ext_vector_type(4))) float f32x4;    // MFMA C/D

static __device__ __forceinline__ ushort_t f2bf(float x) {
  __hip_bfloat16 h = __float2bfloat16(x);
  return *reinterpret_cast<ushort_t*>(&h);
}
static __device__ __forceinline__ unsigned pk2(float a, float b) {
  __hip_bfloat162 t = __float22bfloat162_rn(make_float2(a, b));
  return *reinterpret_cast<unsigned*>(&t);
}
static __device__ __forceinline__ float bf2f(ushort_t u) {
  unsigned x = (unsigned)u << 16;
  return *reinterpret_cast<float*>(&x);
}

// async global->LDS, 16B/lane; LDS dest = wave-uniform base + lane*16
static __device__ __forceinline__ void gl16(const void* g, void* l) {
  __builtin_amdgcn_global_load_lds(
      (const __attribute__((address_space(1))) void*)g,
      (__attribute__((address_space(3))) void*)l, 16, 0, 0);
}

// ---------------------------------------------------------------------------
// Merged prep [validated R10-R14]: z<5 plain fp32->bf16 (E, WO,
// HQ*0.125*log2e, HK, HV); z 5..7 transposing cvt (WQ^T/WK^T/WV^T).
// ---------------------------------------------------------------------------
struct CvtAll {
  const float* src[8];
  ushort_t*    dst[8];
  int          n[8];
  float        scale[8];
};

__global__ __launch_bounds__(256) void cvt_all(CvtAll a) {
  const int z = blockIdx.y;
  if (z < 5) {
    const float4* __restrict__ s = (const float4*)a.src[z];
    ushort_t* __restrict__ d = a.dst[z];
    const float sc = a.scale[z];
    const int n4 = a.n[z] >> 2;
    for (int i = blockIdx.x * blockDim.x + threadIdx.x; i < n4;
         i += gridDim.x * blockDim.x) {
      float4 v = s[i];
      u64 pk = (u64)pk2(v.x * sc, v.y * sc) |
               ((u64)pk2(v.z * sc, v.w * sc) << 32);
      *(u64*)&d[i * 4] = pk;
    }
  } else {
    __shared__ ushort_t T[64][72];
    const float* __restrict__ s = a.src[z];
    ushort_t* __restrict__ d = a.dst[z];
    const int bi = (blockIdx.x >> 4) * 64;   // source row block
    const int bj = (blockIdx.x & 15) * 64;   // source col block
    const int r = threadIdx.x >> 2;
    const int c = (threadIdx.x & 3) * 16;
    const float* sp = s + (size_t)(bi + r) * D_MODEL + bj + c;
    #pragma unroll
    for (int u = 0; u < 4; u++) {
      float4 v = *(const float4*)(sp + u * 4);
      T[c + u*4 + 0][r] = f2bf(v.x);
      T[c + u*4 + 1][r] = f2bf(v.y);
      T[c + u*4 + 2][r] = f2bf(v.z);
      T[c + u*4 + 3][r] = f2bf(v.w);
    }
    __syncthreads();
    ushort_t* dp = d + (size_t)(bj + r) * D_MODEL + bi + c;
    *(short8*)dp       = *(const short8*)&T[r][c];
    *(short8*)(dp + 8) = *(const short8*)&T[r][c + 8];
  }
}

// ---------------------------------------------------------------------------
// bf16 MFMA GEMM: C[M,N] = A @ B^T, 128x128 tile, BK=64 [validated R12-R14].
// Stage phys chunk p -> (row p>>3, col (p&7)^(row&7)) via linear-lane gl_lds;
// read logical chunk c of row r at phys slot c^(r&7).
// CM_QKV: z==2 writes vT[b][he][s] via the R6/R9/R11-validated scatter.
// ---------------------------------------------------------------------------
enum { CM_BF16 = 0, CM_F32 = 1, CM_QKV = 2 };

struct MM3 {
  const ushort_t* a[3];
  const ushort_t* b[3];
  void*           c[3];
};

template<int CM>
__global__ __launch_bounds__(256)
void mm_bf16_bt(MM3 pp, int lda, int ldb, int ldc, int K) {
  __shared__ ushort_t As[128 * 64];
  __shared__ ushort_t Bs[128 * 64];
  const int z = blockIdx.z;
  const ushort_t* __restrict__ A = pp.a[z];
  const ushort_t* __restrict__ B = pp.b[z];
  void* __restrict__ C = pp.c[z];

  const int tid  = threadIdx.x;
  const int lane = tid & 63;
  const int w    = tid >> 6;
  const int ww   = w >> 1, wc = w & 1;
  const int l15  = lane & 15, quad = lane >> 4;
  const int m0 = blockIdx.x * 128;
  const int n0 = blockIdx.y * 128;

  const ushort_t* gA[4];
  const ushort_t* gB[4];
  ushort_t* lA[4];
  ushort_t* lB[4];
  #pragma unroll
  for (int i = 0; i < 4; i++) {
    const int p  = w * 256 + i * 64 + lane;
    const int rw = p >> 3, cc = (p & 7) ^ (rw & 7);
    gA[i] = A + (size_t)(m0 + rw) * lda + cc * 8;
    gB[i] = B + (size_t)(n0 + rw) * ldb + cc * 8;
    lA[i] = &As[(w * 256 + i * 64) * 8];
    lB[i] = &Bs[(w * 256 + i * 64) * 8];
  }

  int iA[4][2], iB[4][2];
  #pragma unroll
  for (int mt = 0; mt < 4; mt++) {
    const int ra = ww * 64 + mt * 16 + l15;
    const int rb = wc * 64 + mt * 16 + l15;
    #pragma unroll
    for (int ks = 0; ks < 2; ks++) {
      iA[mt][ks] = (ra * 8 + ((ks * 4 + quad) ^ (ra & 7))) * 8;
      iB[mt][ks] = (rb * 8 + ((ks * 4 + quad) ^ (rb & 7))) * 8;
    }
  }

  f32x4 acc[4][4];
  #pragma unroll
  for (int i = 0; i < 4; i++)
    #pragma unroll
    for (int j = 0; j < 4; j++) acc[i][j] = (f32x4){0.f, 0.f, 0.f, 0.f};

  for (int k0 = 0; k0 < K; k0 += 64) {
    __syncthreads();
    #pragma unroll
    for (int i = 0; i < 4; i++) {
      gl16(gA[i] + k0, lA[i]);
      gl16(gB[i] + k0, lB[i]);
    }
    __syncthreads();

    #pragma unroll
    for (int ks = 0; ks < 2; ks++) {
      short8 af[4], bf[4];
      #pragma unroll
      for (int mt = 0; mt < 4; mt++) af[mt] = *(const short8*)&As[iA[mt][ks]];
      #pragma unroll
      for (int nt = 0; nt < 4; nt++) bf[nt] = *(const short8*)&Bs[iB[nt][ks]];
      #pragma unroll
      for (int mt = 0; mt < 4; mt++)
        #pragma unroll
        for (int nt = 0; nt < 4; nt++)
          acc[mt][nt] = __builtin_amdgcn_mfma_f32_16x16x32_bf16(
              af[mt], bf[nt], acc[mt][nt], 0, 0, 0);
    }
  }

  if (CM == CM_QKV && z == 2) {
    // [validated R6/R9/R11] vT scatter epilogue: 4 consecutive s -> b64.
    #pragma unroll
    for (int mt = 0; mt < 4; mt++) {
      const int sg = m0 + ww * 64 + mt * 16 + quad * 4;
      const int b = sg >> 11, sl = sg & (SEQ - 1);
      #pragma unroll
      for (int nt = 0; nt < 4; nt++) {
        const int he = n0 + wc * 64 + nt * 16 + l15;
        u64 pk = (u64)pk2(acc[mt][nt][0], acc[mt][nt][1]) |
                 ((u64)pk2(acc[mt][nt][2], acc[mt][nt][3]) << 32);
        *(u64*)&((ushort_t*)C)[((size_t)(b * D_MODEL + he)) * SEQ + sl] = pk;
      }
    }
    return;
  }

  #pragma unroll
  for (int mt = 0; mt < 4; mt++)
    #pragma unroll
    for (int nt = 0; nt < 4; nt++)
      #pragma unroll
      for (int r = 0; r < 4; r++) {
        const size_t row = (size_t)(m0 + ww * 64 + mt * 16 + quad * 4 + r);
        const int    col = n0 + wc * 64 + nt * 16 + l15;
        if (CM == CM_F32)
          ((float*)C)[row * ldc + col] = acc[mt][nt][r];
        else
          ((ushort_t*)C)[row * ldc + col] = f2bf(acc[mt][nt][r]);
      }
}

// ---------------------------------------------------------------------------
// Split-K MFMA flash attention — R14's validated kernel (58.1 µs, 32KB LDS,
// conflicts 2.1e6) with ONE change: NSPLIT 2 -> 4. R14 showed occupancy was
// GRID-limited (1024 blocks = 4/CU; the 5th LDS slot sat empty). 2048 blocks
// (8/CU demand) keep ~5/CU resident through the main phase. Per-block work
// halves (NIT=8); total compute/staging unchanged.
// ---------------------------------------------------------------------------
#define NIT (SEQ / NSPLIT / 64)   // 8

__global__ __launch_bounds__(256)
void flash_split(const ushort_t* __restrict__ q, const ushort_t* __restrict__ k,
                 const ushort_t* __restrict__ vT, ushort_t* __restrict__ Opart,
                 float* __restrict__ lpart) {
  const int q0    = blockIdx.x * 128;
  const int bh    = blockIdx.y;
  const int split = blockIdx.z;
  const int b = bh >> 4, h = bh & 15;
  const size_t row0 = (size_t)b * SEQ;
  const int hc    = h * EHEAD;
  const int kbase = split * (SEQ / NSPLIT);

  __shared__ ushort_t Ks[64 * 64];   // swizzled chunks of [key][e]
  __shared__ ushort_t Vs[64 * 64];   // swizzled chunks of [e][key]
  __shared__ ushort_t Pst[128 * 64]; // swizzled chunks of [q][key]

  const int tid  = threadIdx.x;
  const int lane = tid & 63;
  const int w    = tid >> 6;
  const int l15  = lane & 15;
  const int quad = lane >> 4;
  const int qw   = w * 32;
  const int q7   = l15 & 7;

  // Q fragments in registers (B-operand: col=q=l15, k=quad*8+j)
  short8 bq[2][2];
  #pragma unroll
  for (int nt = 0; nt < 2; nt++) {
    const ushort_t* src = q + (row0 + q0 + qw + nt * 16 + l15) * D_MODEL + hc;
    #pragma unroll
    for (int ks = 0; ks < 2; ks++)
      bq[nt][ks] = *(const short8*)(src + ks * 32 + quad * 8);
  }

  f32x4 ot[4][2];
  float lsum[2] = {0.f, 0.f};
  #pragma unroll
  for (int mt = 0; mt < 4; mt++)
    #pragma unroll
    for (int nt = 0; nt < 2; nt++) ot[mt][nt] = (f32x4){0.f, 0.f, 0.f, 0.f};

  // staging: thread t owns phys chunks p0=t, p1=t+256 of the 512-chunk tile.
  const int p0 = tid, p1 = tid + 256;
  const int rw0 = p0 >> 3, cc0 = (p0 & 7) ^ (rw0 & 7);
  const int rw1 = p1 >> 3, cc1 = (p1 & 7) ^ (rw1 & 7);
  const ushort_t* kg0 = k + (row0 + rw0) * D_MODEL + hc + cc0 * 8;   // +kt*D
  const ushort_t* kg1 = k + (row0 + rw1) * D_MODEL + hc + cc1 * 8;
  const ushort_t* vg0 = vT + ((size_t)(b * D_MODEL + hc + rw0)) * SEQ + cc0 * 8;
  const ushort_t* vg1 = vT + ((size_t)(b * D_MODEL + hc + rw1)) * SEQ + cc1 * 8;

  // K/V frag read offsets [validated R6/R9/R11]
  int kidx[4][2];
  #pragma unroll
  for (int mt = 0; mt < 4; mt++) {
    const int r = mt * 16 + l15;
    #pragma unroll
    for (int ks = 0; ks < 2; ks++)
      kidx[mt][ks] = (r * 8 + ((ks * 4 + quad) ^ (r & 7))) * 8;
  }
  // Pst write offsets [validated R14]: key chunk cl = mt*2 + (quad>>1)
  int pw[4][2];
  #pragma unroll
  for (int mt = 0; mt < 4; mt++)
    #pragma unroll
    for (int nt = 0; nt < 2; nt++) {
      const int qrow = qw + nt * 16 + l15;
      const int cl = mt * 2 + (quad >> 1);
      pw[mt][nt] = (qrow * 8 + (cl ^ q7)) * 8 + (quad & 1) * 4;
    }
  // Pst read offsets (B-operand) [validated R14]
  int pr[2][2];
  #pragma unroll
  for (int nt = 0; nt < 2; nt++)
    #pragma unroll
    for (int ks = 0; ks < 2; ks++) {
      const int qrow = qw + nt * 16 + l15;
      pr[nt][ks] = (qrow * 8 + ((ks * 4 + quad) ^ q7)) * 8;
    }

  short8 kr0, kr1, vr0, vr1;

  // prologue: load + store iter 0
  {
    const size_t ko = (size_t)kbase * D_MODEL;
    kr0 = *(const short8*)(kg0 + ko);
    kr1 = *(const short8*)(kg1 + ko);
    vr0 = *(const short8*)(vg0 + kbase);
    vr1 = *(const short8*)(vg1 + kbase);
  }
  *(short8*)&Ks[p0 * 8] = kr0;
  *(short8*)&Ks[p1 * 8] = kr1;
  *(short8*)&Vs[p0 * 8] = vr0;
  *(short8*)&Vs[p1 * 8] = vr1;

  for (int it = 0; it < NIT; it++) {
    __syncthreads();   // staged LDS visible to all waves

    if (it + 1 < NIT) {
      const int kn = kbase + (it + 1) * 64;
      const size_t ko = (size_t)kn * D_MODEL;
      kr0 = *(const short8*)(kg0 + ko);
      kr1 = *(const short8*)(kg1 + ko);
      vr0 = *(const short8*)(vg0 + kn);
      vr1 = *(const short8*)(vg1 + kn);
    }

    // --- S^T = K . Q^T (Q from registers)
    f32x4 st[4][2];
    #pragma unroll
    for (int mt = 0; mt < 4; mt++)
      #pragma unroll
      for (int nt = 0; nt < 2; nt++) st[mt][nt] = (f32x4){0.f, 0.f, 0.f, 0.f};
    #pragma unroll
    for (int ks = 0; ks < 2; ks++) {
      short8 af[4];
      #pragma unroll
      for (int mt = 0; mt < 4; mt++)
        af[mt] = *(const short8*)&Ks[kidx[mt][ks]];
      #pragma unroll
      for (int mt = 0; mt < 4; mt++)
        #pragma unroll
        for (int nt = 0; nt < 2; nt++)
          st[mt][nt] = __builtin_amdgcn_mfma_f32_16x16x32_bf16(
              af[mt], bq[nt][ks], st[mt][nt], 0, 0, 0);
    }

    // --- native exp2 (log2e pre-folded) + row sums + swizzled b64 P^T writes
    #pragma unroll
    for (int mt = 0; mt < 4; mt++)
      #pragma unroll
      for (int nt = 0; nt < 2; nt++) {
        float e0 = __builtin_amdgcn_exp2f(st[mt][nt][0]);
        float e1 = __builtin_amdgcn_exp2f(st[mt][nt][1]);
        float e2 = __builtin_amdgcn_exp2f(st[mt][nt][2]);
        float e3 = __builtin_amdgcn_exp2f(st[mt][nt][3]);
        lsum[nt] += (e0 + e1) + (e2 + e3);
        u64 pk = (u64)pk2(e0, e1) | ((u64)pk2(e2, e3) << 32);
        *(u64*)&Pst[pw[mt][nt]] = pk;
      }

    // --- O^T += V^T . P^T (same-wave LDS RAW via lgkmcnt)
    #pragma unroll
    for (int ks = 0; ks < 2; ks++) {
      short8 av[4], bp[2];
      #pragma unroll
      for (int mt = 0; mt < 4; mt++)
        av[mt] = *(const short8*)&Vs[kidx[mt][ks]];
      #pragma unroll
      for (int nt = 0; nt < 2; nt++)
        bp[nt] = *(const short8*)&Pst[pr[nt][ks]];
      #pragma unroll
      for (int mt = 0; mt < 4; mt++)
        #pragma unroll
        for (int nt = 0; nt < 2; nt++)
          ot[mt][nt] = __builtin_amdgcn_mfma_f32_16x16x32_bf16(
              av[mt], bp[nt], ot[mt][nt], 0, 0, 0);
    }

    __syncthreads();   // all waves done reading Ks/Vs
    if (it + 1 < NIT) {
      *(short8*)&Ks[p0 * 8] = kr0;
      *(short8*)&Ks[p1 * 8] = kr1;
      *(short8*)&Vs[p0 * 8] = vr0;
      *(short8*)&Vs[p1 * 8] = vr1;
    }
  }

  // --- epilogue: per-split normalize, bf16 partials + fp32 row sums
  #pragma unroll
  for (int nt = 0; nt < 2; nt++) {
    float s = lsum[nt];
    s += __shfl_xor(s, 16);
    s += __shfl_xor(s, 32);
    const float inv = 1.f / s;
    const int qL = q0 + qw + nt * 16 + l15;
    const size_t obase = ((size_t)(split * 32 + bh) * SEQ + qL) * EHEAD;
    #pragma unroll
    for (int mt = 0; mt < 4; mt++) {
      u64 pk = (u64)pk2(ot[mt][nt][0] * inv, ot[mt][nt][1] * inv) |
               ((u64)pk2(ot[mt][nt][2] * inv, ot[mt][nt][3] * inv) << 32);
      *(u64*)&Opart[obase + mt * 16 + quad * 4] = pk;
    }
    if (quad == 0)
      lpart[(size_t)(split * 32 + bh) * SEQ + qL] = s;
  }
}

// ---------------------------------------------------------------------------
// Combine (4-way): ocat = sum_s O_s*l_s / sum_s l_s  (O_s per-split norm'd).
// ---------------------------------------------------------------------------
__global__ __launch_bounds__(256)
void combine_kernel(const ushort_t* __restrict__ Opart,
                    const float* __restrict__ lpart,
                    ushort_t* __restrict__ ocat) {
  const int idx = blockIdx.x * 256 + threadIdx.x;  // 1M threads, 4 e each
  const int e4 = idx & 15;
  const int qq = (idx >> 4) & (SEQ - 1);
  const int bh = idx >> 15;
  const size_t base = ((size_t)bh * SEQ + qq) * EHEAD + e4 * 4;
  const size_t half = (size_t)32 * SEQ * EHEAD;
  u64 o[NSPLIT];
  float l[NSPLIT], lt = 0.f;
  #pragma unroll
  for (int s = 0; s < NSPLIT; s++) {
    o[s] = *(const u64*)&Opart[base + (size_t)s * half];
    l[s] = lpart[(size_t)(s * 32 + bh) * SEQ + qq];
    lt += l[s];
  }
  const float inv = 1.f / lt;
  float r[4] = {0.f, 0.f, 0.f, 0.f};
  #pragma unroll
  for (int s = 0; s < NSPLIT; s++) {
    const float wgt = l[s] * inv;
    #pragma unroll
    for (int j = 0; j < 4; j++)
      r[j] += bf2f((ushort_t)(o[s] >> (16 * j))) * wgt;
  }
  const int b = bh >> 4, h = bh & 15;
  *(u64*)&ocat[((size_t)(b * SEQ + qq)) * D_MODEL + h * EHEAD + e4 * 4] =
      (u64)pk2(r[0], r[1]) | ((u64)pk2(r[2], r[3]) << 32);
}

// ---------------------------------------------------------------------------
// 6 dispatches:
//  0. cvt_all (E, WO, HQ*0.125*log2e, HK, HV plain; WQ/WK/WV transposed)
//  1. Weff_z = H_z @ W_z                 (192 blk, BK=64)
//  2. qkv_z  = E @ Weff_z^T              (768 blk, BK=64; z=2 -> vT scatter)
//  3. flash split-K x4 (2048 blk, 32KB LDS -> ~5 blocks/CU resident)
//  4. combine (4-way) -> ocat
//  5. out = ocat @ WO^T (fp32, BK=64)    (256 blk)
// ws layout: Opart (32MB, written disp 3) aliases the cvt-stage tensors
// Ebf/Hb/Wt/Weff (dead after disp 2). Total 67 MB.
// ---------------------------------------------------------------------------
extern "C" void kernel_launch(void* const* d_in, const int* in_sizes, int n_in,
                              void* d_out, int out_size, void* d_ws, size_t ws_size,
                              hipStream_t stream) {
  const float* E  = (const float*)d_in[0];
  const float* WQ = (const float*)d_in[1];
  const float* WK = (const float*)d_in[2];
  const float* WV = (const float*)d_in[3];
  const float* WO = (const float*)d_in[4];
  const float* HQ = (const float*)d_in[5];
  const float* HK = (const float*)d_in[6];
  const float* HV = (const float*)d_in[7];
  float* out = (float*)d_out;

  const size_t NE = (size_t)BS_ROWS * D_MODEL;  // 4M
  const size_t NW = (size_t)D_MODEL * D_MODEL;  // 1M

  // region A: Opart (disp 3+) aliases cvt-stage tensors (dead after disp 2)
  ushort_t* Opart = (ushort_t*)d_ws;            // NSPLIT*32*SEQ*EHEAD = 16M
  ushort_t* Ebf   = Opart;                      // 4M   (alias, dead@2)
  ushort_t* Hb    = Ebf + NE;                   // 3x1M (alias, dead@1)
  ushort_t* Wt    = Hb + 3 * NW;                // 3x1M (alias, dead@1)
  ushort_t* Weff  = Wt + 3 * NW;                // 3x1M (alias, dead@2) = 13M
  // region B: live through the end
  ushort_t* WOb   = Opart + 4 * NE;             // 1M
  ushort_t* qb    = WOb + NW;                   // 4M
  ushort_t* kb    = qb + NE;                    // 4M
  ushort_t* vTb   = kb + NE;                    // 4M ([b][he][s])
  ushort_t* ocat  = vTb + NE;                   // 4M
  float*    lpart = (float*)(ocat + NE);        // NSPLIT*32*SEQ fp32 = 1MB

  // 0. merged conversions (HQ scale folds 1/sqrt(64) AND log2e)
  {
    CvtAll a;
    const float* s2[8] = {E, WO, HQ, HK, HV, WQ, WK, WV};
    ushort_t* dsts[8] = {Ebf, WOb, Hb, Hb + NW, Hb + 2 * NW,
                         Wt, Wt + NW, Wt + 2 * NW};
    for (int i = 0; i < 8; i++) {
      a.src[i] = s2[i]; a.dst[i] = dsts[i];
      a.n[i] = (i == 0) ? (int)NE : (int)NW;
      a.scale[i] = (i == 2) ? (0.125f * 1.44269504088896f) : 1.0f;
    }
    cvt_all<<<dim3(256, 8), 256, 0, stream>>>(a);
  }
  // 1. Weff_z = H_z @ W_z  (bt-GEMM against W^T)
  {
    MM3 p;
    p.a[0] = Hb; p.a[1] = Hb + NW; p.a[2] = Hb + 2 * NW;
    p.b[0] = Wt; p.b[1] = Wt + NW; p.b[2] = Wt + 2 * NW;
    p.c[0] = Weff; p.c[1] = Weff + NW; p.c[2] = Weff + 2 * NW;
    mm_bf16_bt<CM_BF16><<<dim3(8, 8, 3), 256, 0, stream>>>(
        p, D_MODEL, D_MODEL, D_MODEL, D_MODEL);
  }
  // 2. qkv_z = E @ Weff_z^T  (z=2 -> vT scatter epilogue)
  {
    MM3 p;
    p.a[0] = Ebf; p.a[1] = Ebf; p.a[2] = Ebf;
    p.b[0] = Weff; p.b[1] = Weff + NW; p.b[2] = Weff + 2 * NW;
    p.c[0] = qb; p.c[1] = kb; p.c[2] = vTb;
    mm_bf16_bt<CM_QKV><<<dim3(32, 8, 3), 256, 0, stream>>>(
        p, D_MODEL, D_MODEL, D_MODEL, D_MODEL);
  }
  // 3. flash split-K x4
  flash_split<<<dim3(SEQ / 128, 32, NSPLIT), 256, 0, stream>>>(
      qb, kb, vTb, Opart, lpart);
  // 4. combine
  combine_kernel<<<dim3((32 * SEQ * EHEAD / 4) / 256), 256, 0, stream>>>(
      Opart, lpart, ocat);
  // 5. out = ocat @ WO^T
  {
    MM3 p;
    p.a[0] = ocat; p.b[0] = WOb; p.c[0] = out;
    p.a[1] = ocat; p.b[1] = WOb; p.c[1] = out;
    p.a[2] = ocat; p.b[2] = WOb; p.c[2] = out;
    mm_bf16_bt<CM_F32><<<dim3(32, 8, 1), 256, 0, stream>>>(
        p, D_MODEL, D_MODEL, D_MODEL, D_MODEL);
  }
}

// Round 16
// 216.847 us; speedup vs baseline: 1.0954x; 1.0954x over previous
//
#include <hip/hip_runtime.h>
#include <hip/hip_bf16.h>
#include <math.h>

#define D_MODEL 1024
#define BATCH   2
#define SEQ     2048
#define NHEAD   16
#define EHEAD   64
#define BS_ROWS (BATCH*SEQ)   // 4096
#define NSPLIT  2

typedef unsigned short ushort_t;
typedef unsigned long long u64;
typedef __attribute__((ext_vector_type(8))) short short8;   // 8 bf16 = 4 VGPRs
typedef __attribute__((ext_vector_type(4))) float f32x4;    // MFMA C/D

static __device__ __forceinline__ ushort_t f2bf(float x) {
  __hip_bfloat16 h = __float2bfloat16(x);
  return *reinterpret_cast<ushort_t*>(&h);
}
static __device__ __forceinline__ unsigned pk2(float a, float b) {
  __hip_bfloat162 t = __float22bfloat162_rn(make_float2(a, b));
  return *reinterpret_cast<unsigned*>(&t);
}
static __device__ __forceinline__ float bf2f(ushort_t u) {
  unsigned x = (unsigned)u << 16;
  return *reinterpret_cast<float*>(&x);
}

// async global->LDS, 16B/lane; LDS dest = wave-uniform base + lane*16
static __device__ __forceinline__ void gl16(const void* g, void* l) {
  __builtin_amdgcn_global_load_lds(
      (const __attribute__((address_space(1))) void*)g,
      (__attribute__((address_space(3))) void*)l, 16, 0, 0);
}

// ---------------------------------------------------------------------------
// Merged prep [validated R10-R15]: z<5 plain fp32->bf16 (E, WO,
// HQ*0.125*log2e, HK, HV); z 5..7 transposing cvt (WQ^T/WK^T/WV^T).
// ---------------------------------------------------------------------------
struct CvtAll {
  const float* src[8];
  ushort_t*    dst[8];
  int          n[8];
  float        scale[8];
};

__global__ __launch_bounds__(256) void cvt_all(CvtAll a) {
  const int z = blockIdx.y;
  if (z < 5) {
    const float4* __restrict__ s = (const float4*)a.src[z];
    ushort_t* __restrict__ d = a.dst[z];
    const float sc = a.scale[z];
    const int n4 = a.n[z] >> 2;
    for (int i = blockIdx.x * blockDim.x + threadIdx.x; i < n4;
         i += gridDim.x * blockDim.x) {
      float4 v = s[i];
      u64 pk = (u64)pk2(v.x * sc, v.y * sc) |
               ((u64)pk2(v.z * sc, v.w * sc) << 32);
      *(u64*)&d[i * 4] = pk;
    }
  } else {
    __shared__ ushort_t T[64][72];
    const float* __restrict__ s = a.src[z];
    ushort_t* __restrict__ d = a.dst[z];
    const int bi = (blockIdx.x >> 4) * 64;   // source row block
    const int bj = (blockIdx.x & 15) * 64;   // source col block
    const int r = threadIdx.x >> 2;
    const int c = (threadIdx.x & 3) * 16;
    const float* sp = s + (size_t)(bi + r) * D_MODEL + bj + c;
    #pragma unroll
    for (int u = 0; u < 4; u++) {
      float4 v = *(const float4*)(sp + u * 4);
      T[c + u*4 + 0][r] = f2bf(v.x);
      T[c + u*4 + 1][r] = f2bf(v.y);
      T[c + u*4 + 2][r] = f2bf(v.z);
      T[c + u*4 + 3][r] = f2bf(v.w);
    }
    __syncthreads();
    ushort_t* dp = d + (size_t)(bj + r) * D_MODEL + bi + c;
    *(short8*)dp       = *(const short8*)&T[r][c];
    *(short8*)(dp + 8) = *(const short8*)&T[r][c + 8];
  }
}

struct MM3 {
  const ushort_t* a[3];
  const ushort_t* b[3];
  void*           c[3];
};

// ---------------------------------------------------------------------------
// 128x128 bf16 MFMA GEMM, BK=64 [validated R12-R15]. Used for qkv (768 blk,
// 3/CU: supply is fine). z==2 writes vT[b][he][s] via the validated scatter.
// ---------------------------------------------------------------------------
__global__ __launch_bounds__(256)
void mm_bf16_qkv(MM3 pp, int lda, int ldb, int ldc, int K) {
  __shared__ ushort_t As[128 * 64];
  __shared__ ushort_t Bs[128 * 64];
  const int z = blockIdx.z;
  const ushort_t* __restrict__ A = pp.a[z];
  const ushort_t* __restrict__ B = pp.b[z];
  void* __restrict__ C = pp.c[z];

  const int tid  = threadIdx.x;
  const int lane = tid & 63;
  const int w    = tid >> 6;
  const int ww   = w >> 1, wc = w & 1;
  const int l15  = lane & 15, quad = lane >> 4;
  const int m0 = blockIdx.x * 128;
  const int n0 = blockIdx.y * 128;

  const ushort_t* gA[4];
  const ushort_t* gB[4];
  ushort_t* lA[4];
  ushort_t* lB[4];
  #pragma unroll
  for (int i = 0; i < 4; i++) {
    const int p  = w * 256 + i * 64 + lane;
    const int rw = p >> 3, cc = (p & 7) ^ (rw & 7);
    gA[i] = A + (size_t)(m0 + rw) * lda + cc * 8;
    gB[i] = B + (size_t)(n0 + rw) * ldb + cc * 8;
    lA[i] = &As[(w * 256 + i * 64) * 8];
    lB[i] = &Bs[(w * 256 + i * 64) * 8];
  }

  int iA[4][2], iB[4][2];
  #pragma unroll
  for (int mt = 0; mt < 4; mt++) {
    const int ra = ww * 64 + mt * 16 + l15;
    const int rb = wc * 64 + mt * 16 + l15;
    #pragma unroll
    for (int ks = 0; ks < 2; ks++) {
      iA[mt][ks] = (ra * 8 + ((ks * 4 + quad) ^ (ra & 7))) * 8;
      iB[mt][ks] = (rb * 8 + ((ks * 4 + quad) ^ (rb & 7))) * 8;
    }
  }

  f32x4 acc[4][4];
  #pragma unroll
  for (int i = 0; i < 4; i++)
    #pragma unroll
    for (int j = 0; j < 4; j++) acc[i][j] = (f32x4){0.f, 0.f, 0.f, 0.f};

  for (int k0 = 0; k0 < K; k0 += 64) {
    __syncthreads();
    #pragma unroll
    for (int i = 0; i < 4; i++) {
      gl16(gA[i] + k0, lA[i]);
      gl16(gB[i] + k0, lB[i]);
    }
    __syncthreads();

    #pragma unroll
    for (int ks = 0; ks < 2; ks++) {
      short8 af[4], bf[4];
      #pragma unroll
      for (int mt = 0; mt < 4; mt++) af[mt] = *(const short8*)&As[iA[mt][ks]];
      #pragma unroll
      for (int nt = 0; nt < 4; nt++) bf[nt] = *(const short8*)&Bs[iB[nt][ks]];
      #pragma unroll
      for (int mt = 0; mt < 4; mt++)
        #pragma unroll
        for (int nt = 0; nt < 4; nt++)
          acc[mt][nt] = __builtin_amdgcn_mfma_f32_16x16x32_bf16(
              af[mt], bf[nt], acc[mt][nt], 0, 0, 0);
    }
  }

  if (z == 2) {
    // [validated R6/R9/R11] vT scatter epilogue: 4 consecutive s -> b64.
    #pragma unroll
    for (int mt = 0; mt < 4; mt++) {
      const int sg = m0 + ww * 64 + mt * 16 + quad * 4;
      const int b = sg >> 11, sl = sg & (SEQ - 1);
      #pragma unroll
      for (int nt = 0; nt < 4; nt++) {
        const int he = n0 + wc * 64 + nt * 16 + l15;
        u64 pk = (u64)pk2(acc[mt][nt][0], acc[mt][nt][1]) |
                 ((u64)pk2(acc[mt][nt][2], acc[mt][nt][3]) << 32);
        *(u64*)&((ushort_t*)C)[((size_t)(b * D_MODEL + he)) * SEQ + sl] = pk;
      }
    }
    return;
  }

  #pragma unroll
  for (int mt = 0; mt < 4; mt++)
    #pragma unroll
    for (int nt = 0; nt < 4; nt++)
      #pragma unroll
      for (int r = 0; r < 4; r++) {
        const size_t row = (size_t)(m0 + ww * 64 + mt * 16 + quad * 4 + r);
        const int    col = n0 + wc * 64 + nt * 16 + l15;
        ((ushort_t*)C)[row * ldc + col] = f2bf(acc[mt][nt][r]);
      }
}

// ---------------------------------------------------------------------------
// R16: 64x64-tile BK=64 GEMM for the grid-starved dispatches (Weff 192->768
// blocks, out 256->1024 blocks). 4 waves in 2x2, each wave 32x32 (2x2 MFMA
// grid). Staging = flash's validated 512-chunk map (p -> row p>>3, col
// (p&7)^(row&7); thread t stages p0=t, p1=t+256 via gl16 with linear-lane LDS
// dests); frag reads = R12's validated slot=c^(r&7). LDS 16KB.
// ---------------------------------------------------------------------------
template<typename OutT>
__global__ __launch_bounds__(256)
void mm64_bt(MM3 pp, int lda, int ldb, int ldc, int K) {
  __shared__ ushort_t As[64 * 64];
  __shared__ ushort_t Bs[64 * 64];
  const int z = blockIdx.z;
  const ushort_t* __restrict__ A = pp.a[z];
  const ushort_t* __restrict__ B = pp.b[z];
  void* __restrict__ C = pp.c[z];

  const int tid  = threadIdx.x;
  const int lane = tid & 63;
  const int w    = tid >> 6;
  const int wm   = w >> 1, wn = w & 1;
  const int l15  = lane & 15, quad = lane >> 4;
  const int m0 = blockIdx.x * 64;
  const int n0 = blockIdx.y * 64;

  const int p0 = tid, p1 = tid + 256;
  const int rw0 = p0 >> 3, cc0 = (p0 & 7) ^ (rw0 & 7);
  const int rw1 = p1 >> 3, cc1 = (p1 & 7) ^ (rw1 & 7);
  const ushort_t* gA0 = A + (size_t)(m0 + rw0) * lda + cc0 * 8;
  const ushort_t* gA1 = A + (size_t)(m0 + rw1) * lda + cc1 * 8;
  const ushort_t* gB0 = B + (size_t)(n0 + rw0) * ldb + cc0 * 8;
  const ushort_t* gB1 = B + (size_t)(n0 + rw1) * ldb + cc1 * 8;
  ushort_t* lA0 = &As[(w * 64) * 8];         // chunks w*64+lane
  ushort_t* lA1 = &As[(256 + w * 64) * 8];
  ushort_t* lB0 = &Bs[(w * 64) * 8];
  ushort_t* lB1 = &Bs[(256 + w * 64) * 8];

  int iA[2][2], iB[2][2];
  #pragma unroll
  for (int mt = 0; mt < 2; mt++) {
    const int ra = wm * 32 + mt * 16 + l15;
    const int rb = wn * 32 + mt * 16 + l15;
    #pragma unroll
    for (int ks = 0; ks < 2; ks++) {
      iA[mt][ks] = (ra * 8 + ((ks * 4 + quad) ^ (ra & 7))) * 8;
      iB[mt][ks] = (rb * 8 + ((ks * 4 + quad) ^ (rb & 7))) * 8;
    }
  }

  f32x4 acc[2][2];
  #pragma unroll
  for (int i = 0; i < 2; i++)
    #pragma unroll
    for (int j = 0; j < 2; j++) acc[i][j] = (f32x4){0.f, 0.f, 0.f, 0.f};

  for (int k0 = 0; k0 < K; k0 += 64) {
    __syncthreads();
    gl16(gA0 + k0, lA0);
    gl16(gA1 + k0, lA1);
    gl16(gB0 + k0, lB0);
    gl16(gB1 + k0, lB1);
    __syncthreads();

    #pragma unroll
    for (int ks = 0; ks < 2; ks++) {
      short8 af[2], bf[2];
      #pragma unroll
      for (int mt = 0; mt < 2; mt++) af[mt] = *(const short8*)&As[iA[mt][ks]];
      #pragma unroll
      for (int nt = 0; nt < 2; nt++) bf[nt] = *(const short8*)&Bs[iB[nt][ks]];
      #pragma unroll
      for (int mt = 0; mt < 2; mt++)
        #pragma unroll
        for (int nt = 0; nt < 2; nt++)
          acc[mt][nt] = __builtin_amdgcn_mfma_f32_16x16x32_bf16(
              af[mt], bf[nt], acc[mt][nt], 0, 0, 0);
    }
  }

  #pragma unroll
  for (int mt = 0; mt < 2; mt++)
    #pragma unroll
    for (int nt = 0; nt < 2; nt++)
      #pragma unroll
      for (int r = 0; r < 4; r++) {
        const size_t row = (size_t)(m0 + wm * 32 + mt * 16 + quad * 4 + r);
        const int    col = n0 + wn * 32 + nt * 16 + l15;
        if constexpr (__is_same(OutT, float))
          ((float*)C)[row * ldc + col] = acc[mt][nt][r];
        else
          ((ushort_t*)C)[row * ldc + col] = f2bf(acc[mt][nt][r]);
      }
}

// ---------------------------------------------------------------------------
// Split-K MFMA flash attention — R14's kernel VERBATIM (58.1 µs, the best
// measured; NSPLIT=2 is the optimum — R15's x4 lost to per-block overhead).
// 32KB LDS, swizzled Ks/Vs/Pst, register prefetch, native exp2, no-max
// softmax, bf16 per-split-normalized partials.
// ---------------------------------------------------------------------------
#define NIT (SEQ / NSPLIT / 64)   // 16

__global__ __launch_bounds__(256)
void flash_split(const ushort_t* __restrict__ q, const ushort_t* __restrict__ k,
                 const ushort_t* __restrict__ vT, ushort_t* __restrict__ Opart,
                 float* __restrict__ lpart) {
  const int q0    = blockIdx.x * 128;
  const int bh    = blockIdx.y;
  const int split = blockIdx.z;
  const int b = bh >> 4, h = bh & 15;
  const size_t row0 = (size_t)b * SEQ;
  const int hc    = h * EHEAD;
  const int kbase = split * (SEQ / NSPLIT);

  __shared__ ushort_t Ks[64 * 64];   // swizzled chunks of [key][e]
  __shared__ ushort_t Vs[64 * 64];   // swizzled chunks of [e][key]
  __shared__ ushort_t Pst[128 * 64]; // swizzled chunks of [q][key]

  const int tid  = threadIdx.x;
  const int lane = tid & 63;
  const int w    = tid >> 6;
  const int l15  = lane & 15;
  const int quad = lane >> 4;
  const int qw   = w * 32;
  const int q7   = l15 & 7;

  // Q fragments in registers (B-operand: col=q=l15, k=quad*8+j)
  short8 bq[2][2];
  #pragma unroll
  for (int nt = 0; nt < 2; nt++) {
    const ushort_t* src = q + (row0 + q0 + qw + nt * 16 + l15) * D_MODEL + hc;
    #pragma unroll
    for (int ks = 0; ks < 2; ks++)
      bq[nt][ks] = *(const short8*)(src + ks * 32 + quad * 8);
  }

  f32x4 ot[4][2];
  float lsum[2] = {0.f, 0.f};
  #pragma unroll
  for (int mt = 0; mt < 4; mt++)
    #pragma unroll
    for (int nt = 0; nt < 2; nt++) ot[mt][nt] = (f32x4){0.f, 0.f, 0.f, 0.f};

  const int p0 = tid, p1 = tid + 256;
  const int rw0 = p0 >> 3, cc0 = (p0 & 7) ^ (rw0 & 7);
  const int rw1 = p1 >> 3, cc1 = (p1 & 7) ^ (rw1 & 7);
  const ushort_t* kg0 = k + (row0 + rw0) * D_MODEL + hc + cc0 * 8;   // +kt*D
  const ushort_t* kg1 = k + (row0 + rw1) * D_MODEL + hc + cc1 * 8;
  const ushort_t* vg0 = vT + ((size_t)(b * D_MODEL + hc + rw0)) * SEQ + cc0 * 8;
  const ushort_t* vg1 = vT + ((size_t)(b * D_MODEL + hc + rw1)) * SEQ + cc1 * 8;

  int kidx[4][2];
  #pragma unroll
  for (int mt = 0; mt < 4; mt++) {
    const int r = mt * 16 + l15;
    #pragma unroll
    for (int ks = 0; ks < 2; ks++)
      kidx[mt][ks] = (r * 8 + ((ks * 4 + quad) ^ (r & 7))) * 8;
  }
  int pw[4][2];
  #pragma unroll
  for (int mt = 0; mt < 4; mt++)
    #pragma unroll
    for (int nt = 0; nt < 2; nt++) {
      const int qrow = qw + nt * 16 + l15;
      const int cl = mt * 2 + (quad >> 1);
      pw[mt][nt] = (qrow * 8 + (cl ^ q7)) * 8 + (quad & 1) * 4;
    }
  int pr[2][2];
  #pragma unroll
  for (int nt = 0; nt < 2; nt++)
    #pragma unroll
    for (int ks = 0; ks < 2; ks++) {
      const int qrow = qw + nt * 16 + l15;
      pr[nt][ks] = (qrow * 8 + ((ks * 4 + quad) ^ q7)) * 8;
    }

  short8 kr0, kr1, vr0, vr1;

  {
    const size_t ko = (size_t)kbase * D_MODEL;
    kr0 = *(const short8*)(kg0 + ko);
    kr1 = *(const short8*)(kg1 + ko);
    vr0 = *(const short8*)(vg0 + kbase);
    vr1 = *(const short8*)(vg1 + kbase);
  }
  *(short8*)&Ks[p0 * 8] = kr0;
  *(short8*)&Ks[p1 * 8] = kr1;
  *(short8*)&Vs[p0 * 8] = vr0;
  *(short8*)&Vs[p1 * 8] = vr1;

  for (int it = 0; it < NIT; it++) {
    __syncthreads();   // staged LDS visible to all waves

    if (it + 1 < NIT) {
      const int kn = kbase + (it + 1) * 64;
      const size_t ko = (size_t)kn * D_MODEL;
      kr0 = *(const short8*)(kg0 + ko);
      kr1 = *(const short8*)(kg1 + ko);
      vr0 = *(const short8*)(vg0 + kn);
      vr1 = *(const short8*)(vg1 + kn);
    }

    // --- S^T = K . Q^T (Q from registers)
    f32x4 st[4][2];
    #pragma unroll
    for (int mt = 0; mt < 4; mt++)
      #pragma unroll
      for (int nt = 0; nt < 2; nt++) st[mt][nt] = (f32x4){0.f, 0.f, 0.f, 0.f};
    #pragma unroll
    for (int ks = 0; ks < 2; ks++) {
      short8 af[4];
      #pragma unroll
      for (int mt = 0; mt < 4; mt++)
        af[mt] = *(const short8*)&Ks[kidx[mt][ks]];
      #pragma unroll
      for (int mt = 0; mt < 4; mt++)
        #pragma unroll
        for (int nt = 0; nt < 2; nt++)
          st[mt][nt] = __builtin_amdgcn_mfma_f32_16x16x32_bf16(
              af[mt], bq[nt][ks], st[mt][nt], 0, 0, 0);
    }

    // --- native exp2 (log2e pre-folded) + row sums + swizzled b64 P^T writes
    #pragma unroll
    for (int mt = 0; mt < 4; mt++)
      #pragma unroll
      for (int nt = 0; nt < 2; nt++) {
        float e0 = __builtin_amdgcn_exp2f(st[mt][nt][0]);
        float e1 = __builtin_amdgcn_exp2f(st[mt][nt][1]);
        float e2 = __builtin_amdgcn_exp2f(st[mt][nt][2]);
        float e3 = __builtin_amdgcn_exp2f(st[mt][nt][3]);
        lsum[nt] += (e0 + e1) + (e2 + e3);
        u64 pk = (u64)pk2(e0, e1) | ((u64)pk2(e2, e3) << 32);
        *(u64*)&Pst[pw[mt][nt]] = pk;
      }

    // --- O^T += V^T . P^T (same-wave LDS RAW via lgkmcnt)
    #pragma unroll
    for (int ks = 0; ks < 2; ks++) {
      short8 av[4], bp[2];
      #pragma unroll
      for (int mt = 0; mt < 4; mt++)
        av[mt] = *(const short8*)&Vs[kidx[mt][ks]];
      #pragma unroll
      for (int nt = 0; nt < 2; nt++)
        bp[nt] = *(const short8*)&Pst[pr[nt][ks]];
      #pragma unroll
      for (int mt = 0; mt < 4; mt++)
        #pragma unroll
        for (int nt = 0; nt < 2; nt++)
          ot[mt][nt] = __builtin_amdgcn_mfma_f32_16x16x32_bf16(
              av[mt], bp[nt], ot[mt][nt], 0, 0, 0);
    }

    __syncthreads();   // all waves done reading Ks/Vs
    if (it + 1 < NIT) {
      *(short8*)&Ks[p0 * 8] = kr0;
      *(short8*)&Ks[p1 * 8] = kr1;
      *(short8*)&Vs[p0 * 8] = vr0;
      *(short8*)&Vs[p1 * 8] = vr1;
    }
  }

  // --- epilogue: per-split normalize, bf16 partials + fp32 row sums
  #pragma unroll
  for (int nt = 0; nt < 2; nt++) {
    float s = lsum[nt];
    s += __shfl_xor(s, 16);
    s += __shfl_xor(s, 32);
    const float inv = 1.f / s;
    const int qL = q0 + qw + nt * 16 + l15;
    const size_t obase = ((size_t)(split * 32 + bh) * SEQ + qL) * EHEAD;
    #pragma unroll
    for (int mt = 0; mt < 4; mt++) {
      u64 pk = (u64)pk2(ot[mt][nt][0] * inv, ot[mt][nt][1] * inv) |
               ((u64)pk2(ot[mt][nt][2] * inv, ot[mt][nt][3] * inv) << 32);
      *(u64*)&Opart[obase + mt * 16 + quad * 4] = pk;
    }
    if (quad == 0)
      lpart[(size_t)(split * 32 + bh) * SEQ + qL] = s;
  }
}

// ---------------------------------------------------------------------------
// Combine (NSPLIT-way weighted avg of per-split-normalized partials).
// [validated R6/R8/R10-R15]
// ---------------------------------------------------------------------------
__global__ __launch_bounds__(256)
void combine_kernel(const ushort_t* __restrict__ Opart,
                    const float* __restrict__ lpart,
                    ushort_t* __restrict__ ocat) {
  const int idx = blockIdx.x * 256 + threadIdx.x;  // 1M threads, 4 e each
  const int e4 = idx & 15;
  const int qq = (idx >> 4) & (SEQ - 1);
  const int bh = idx >> 15;
  const size_t base = ((size_t)bh * SEQ + qq) * EHEAD + e4 * 4;
  const size_t half = (size_t)32 * SEQ * EHEAD;
  u64 o[NSPLIT];
  float l[NSPLIT], lt = 0.f;
  #pragma unroll
  for (int s = 0; s < NSPLIT; s++) {
    o[s] = *(const u64*)&Opart[base + (size_t)s * half];
    l[s] = lpart[(size_t)(s * 32 + bh) * SEQ + qq];
    lt += l[s];
  }
  const float inv = 1.f / lt;
  float r[4] = {0.f, 0.f, 0.f, 0.f};
  #pragma unroll
  for (int s = 0; s < NSPLIT; s++) {
    const float wgt = l[s] * inv;
    #pragma unroll
    for (int j = 0; j < 4; j++)
      r[j] += bf2f((ushort_t)(o[s] >> (16 * j))) * wgt;
  }
  const int b = bh >> 4, h = bh & 15;
  *(u64*)&ocat[((size_t)(b * SEQ + qq)) * D_MODEL + h * EHEAD + e4 * 4] =
      (u64)pk2(r[0], r[1]) | ((u64)pk2(r[2], r[3]) << 32);
}

// ---------------------------------------------------------------------------
// 6 dispatches:
//  0. cvt_all (E, WO, HQ*0.125*log2e, HK, HV plain; WQ/WK/WV transposed)
//  1. Weff_z = H_z @ W_z          (mm64: 768 blk, was 192 — grid-starved)
//  2. qkv_z  = E @ Weff_z^T       (128-tile, 768 blk; z=2 -> vT scatter)
//  3. flash split-K x2            (R14 kernel, 1024 blk, 32KB LDS)
//  4. combine -> ocat
//  5. out = ocat @ WO^T (fp32)    (mm64: 1024 blk, was 256 — grid-starved)
// ws: 76.5 MB (R14 layout).
// ---------------------------------------------------------------------------
extern "C" void kernel_launch(void* const* d_in, const int* in_sizes, int n_in,
                              void* d_out, int out_size, void* d_ws, size_t ws_size,
                              hipStream_t stream) {
  const float* E  = (const float*)d_in[0];
  const float* WQ = (const float*)d_in[1];
  const float* WK = (const float*)d_in[2];
  const float* WV = (const float*)d_in[3];
  const float* WO = (const float*)d_in[4];
  const float* HQ = (const float*)d_in[5];
  const float* HK = (const float*)d_in[6];
  const float* HV = (const float*)d_in[7];
  float* out = (float*)d_out;

  const size_t NE = (size_t)BS_ROWS * D_MODEL;  // 4M
  const size_t NW = (size_t)D_MODEL * D_MODEL;  // 1M

  ushort_t* Ebf   = (ushort_t*)d_ws;            // 4M
  ushort_t* WOb   = Ebf + NE;                   // 1M
  ushort_t* Hb    = WOb + NW;                   // 3 x 1M
  ushort_t* Wt    = Hb + 3 * NW;                // 3 x 1M (W^T)
  ushort_t* Weff  = Wt + 3 * NW;                // 3 x 1M
  ushort_t* qb    = Weff + 3 * NW;              // 4M
  ushort_t* kb    = qb + NE;                    // 4M
  ushort_t* vTb   = kb + NE;                    // 4M ([b][he][s])
  ushort_t* ocat  = vTb + NE;                   // 4M
  ushort_t* Opart = ocat + NE;                  // 8M bf16
  float*    lpart = (float*)(Opart + 2 * NE);   // 128K fp32

  // 0. merged conversions (HQ scale folds 1/sqrt(64) AND log2e)
  {
    CvtAll a;
    const float* s2[8] = {E, WO, HQ, HK, HV, WQ, WK, WV};
    ushort_t* dsts[8] = {Ebf, WOb, Hb, Hb + NW, Hb + 2 * NW,
                         Wt, Wt + NW, Wt + 2 * NW};
    for (int i = 0; i < 8; i++) {
      a.src[i] = s2[i]; a.dst[i] = dsts[i];
      a.n[i] = (i == 0) ? (int)NE : (int)NW;
      a.scale[i] = (i == 2) ? (0.125f * 1.44269504088896f) : 1.0f;
    }
    cvt_all<<<dim3(256, 8), 256, 0, stream>>>(a);
  }
  // 1. Weff_z = H_z @ W_z  (64-tile bt-GEMM against W^T; 768 blocks)
  {
    MM3 p;
    p.a[0] = Hb; p.a[1] = Hb + NW; p.a[2] = Hb + 2 * NW;
    p.b[0] = Wt; p.b[1] = Wt + NW; p.b[2] = Wt + 2 * NW;
    p.c[0] = Weff; p.c[1] = Weff + NW; p.c[2] = Weff + 2 * NW;
    mm64_bt<ushort_t><<<dim3(16, 16, 3), 256, 0, stream>>>(
        p, D_MODEL, D_MODEL, D_MODEL, D_MODEL);
  }
  // 2. qkv_z = E @ Weff_z^T  (z=2 -> vT scatter epilogue)
  {
    MM3 p;
    p.a[0] = Ebf; p.a[1] = Ebf; p.a[2] = Ebf;
    p.b[0] = Weff; p.b[1] = Weff + NW; p.b[2] = Weff + 2 * NW;
    p.c[0] = qb; p.c[1] = kb; p.c[2] = vTb;
    mm_bf16_qkv<<<dim3(32, 8, 3), 256, 0, stream>>>(
        p, D_MODEL, D_MODEL, D_MODEL, D_MODEL);
  }
  // 3. flash split-K x2
  flash_split<<<dim3(SEQ / 128, 32, NSPLIT), 256, 0, stream>>>(
      qb, kb, vTb, Opart, lpart);
  // 4. combine
  combine_kernel<<<dim3((32 * SEQ * EHEAD / 4) / 256), 256, 0, stream>>>(
      Opart, lpart, ocat);
  // 5. out = ocat @ WO^T  (64-tile; 1024 blocks)
  {
    MM3 p;
    p.a[0] = ocat; p.b[0] = WOb; p.c[0] = out;
    p.a[1] = ocat; p.b[1] = WOb; p.c[1] = out;
    p.a[2] = ocat; p.b[2] = WOb; p.c[2] = out;
    mm64_bt<float><<<dim3(64, 16, 1), 256, 0, stream>>>(
        p, D_MODEL, D_MODEL, D_MODEL, D_MODEL);
  }
}